// Round 1
// baseline (681.649 us; speedup 1.0000x reference)
//
#include <hip/hip_runtime.h>
#include <math.h>

// CapsLayer dynamic routing, MI355X fp32.
// x: [64, 2048, 8]  W: [2048, 32, 8, 16]  out: [64, 32, 16]
// Never materialize u_hat (256 MB); recompute per routing pass.
// R3: latency-bound fix #2 — route_pass was 50us with VALUBusy 16% / Occ 25%
// (every throughput pipe <=30% of ceiling => exposed L2/L3 load latency).
//   * ICH 16->8: grid 1024->2048 blocks = 8 blocks/CU = 32 waves/CU (HW cap).
//     Same W traffic, same per-thread instruction mix; pure TLP gain.
//     VGPR stays well under 64 so __launch_bounds__(256,8) is safe.
//   * aws eliminated: iter2 logits u.v0 + u.v1 == u.(v0+v1) (dot is linear),
//     so pass 3 is just MODE1 with vin = v0+v1 (computed in pass-2 reduce).
//     Saves 16MB write + 16MB read; keeps workspace at 32.25 MB.
//   * reduce_squash parallelized: 512 blocks (one per (b, 64-out slice)),
//     4-way ic split + LDS combine -> all 256 CUs active.

#define B_TOT 64
#define I_TOT 2048
#define D_IN  8
#define NC    32
#define EV    16
#define OD    (NC*EV)      // 512 outputs per b
#define BC    8            // batch rows per block
#define NBC   (B_TOT/BC)   // 8 b-chunks
#define ICH   8            // i's per block
#define NIC   (I_TOT/ICH)  // 256 i-chunks

__device__ __forceinline__ void fma4(float4& acc, float a, const float4& w) {
    acc.x = fmaf(a, w.x, acc.x);
    acc.y = fmaf(a, w.y, acc.y);
    acc.z = fmaf(a, w.z, acc.z);
    acc.w = fmaf(a, w.w, acc.w);
}

// MODE 0: c uniform (iter 0)              -> P partials
// MODE 1: c = softmax_n(u . vin)          -> P partials
//         (iter 2 uses vin = v0+v1: dot is linear, so no logit carry needed)
template <int MODE>
__global__ __launch_bounds__(256, 8)
void route_pass(const float* __restrict__ x, const float* __restrict__ W,
                float* __restrict__ P, const float* __restrict__ vin)
{
    __shared__ __align__(16) float xl[BC * ICH * D_IN];   // 2 KB
    __shared__ float wsum[2][4][BC];                      // 256 B (double-buffered)

    const int t  = threadIdx.x;
    // XCD swizzle: blk%8 == ic%8, so the 8 bc-siblings of an ic (which share
    // W[i0..i0+7]) land on the same XCD's L2. Per-XCD W working set = 4 MB.
    const int ic = blockIdx.x & (NIC - 1);   // 0..255
    const int bc = blockIdx.x >> 8;          // 0..7
    const int b0 = bc * BC;
    const int i0 = ic * ICH;
    const int eq = t & 3;          // e quarter (4 e's)
    const int bh = (t >> 2) & 1;   // b half (4 b's each)
    const int n  = t >> 3;         // capsule 0..31
    const int w  = t >> 6;         // wave 0..3

    // ---- stage x[b0..b0+7][i0..i0+7][0..7] once (2 KB) ----
    if (t < 128) {
        const int row = t >> 4, f = (t & 15) * 4;
        *(float4*)&xl[row * (ICH * D_IN) + f] =
            *(const float4*)&x[((size_t)(b0 + row) * I_TOT + i0) * D_IN + f];
    }

    // ---- v fragments in registers (loaded once; L2-hot, tiny) ----
    float4 vr[4];
    if (MODE == 1) {
        #pragma unroll
        for (int q = 0; q < 4; ++q)
            vr[q] = *(const float4*)&vin[(size_t)(b0 + bh * 4 + q) * OD + n * EV + eq * 4];
    }
    __syncthreads();

    float4 sacc[4];
    #pragma unroll
    for (int q = 0; q < 4; ++q) sacc[q] = make_float4(0.f, 0.f, 0.f, 0.f);

    const float* Wt = &W[(size_t)i0 * 4096 + n * 128 + eq * 4];

    for (int ii = 0; ii < ICH; ++ii) {
        // ---- this thread's W fragment straight from global (64B-coalesced) ----
        float4 wr[8];
        #pragma unroll
        for (int d = 0; d < 8; ++d)
            wr[d] = *(const float4*)&Wt[ii * 4096 + d * 16];

        // ---- u[bl][eq*4..+3] for 4 batch rows ----
        float4 u[4];
        #pragma unroll
        for (int q = 0; q < 4; ++q) {
            const int bl = bh * 4 + q;
            float4 xa = *(float4*)&xl[bl * (ICH * D_IN) + ii * 8];
            float4 xb = *(float4*)&xl[bl * (ICH * D_IN) + ii * 8 + 4];
            float4 uu = make_float4(0.f, 0.f, 0.f, 0.f);
            fma4(uu, xa.x, wr[0]); fma4(uu, xa.y, wr[1]);
            fma4(uu, xa.z, wr[2]); fma4(uu, xa.w, wr[3]);
            fma4(uu, xb.x, wr[4]); fma4(uu, xb.y, wr[5]);
            fma4(uu, xb.z, wr[6]); fma4(uu, xb.w, wr[7]);
            u[q] = uu;
        }

        if (MODE == 0) {
            #pragma unroll
            for (int q = 0; q < 4; ++q) {
                sacc[q].x += u[q].x; sacc[q].y += u[q].y;
                sacc[q].z += u[q].z; sacc[q].w += u[q].w;
            }
            // no barrier: xl is read-only, no LDS communication
        } else {
            // ---- a[bl] = dot(u, v) over e: 4 in-thread + shfl over eq bits ----
            float a[4];
            #pragma unroll
            for (int q = 0; q < 4; ++q) {
                float ap = u[q].x * vr[q].x + u[q].y * vr[q].y
                         + u[q].z * vr[q].z + u[q].w * vr[q].w;
                ap += __shfl_xor(ap, 1, 64);
                ap += __shfl_xor(ap, 2, 64);
                a[q] = ap;
            }
            // ---- softmax over n: exp, in-wave partial over this wave's 8 n's ----
            float e[4], p[4];
            #pragma unroll
            for (int q = 0; q < 4; ++q) {
                e[q] = __expf(a[q]);
                float pp = e[q];
                pp += __shfl_xor(pp, 8, 64);
                pp += __shfl_xor(pp, 16, 64);
                pp += __shfl_xor(pp, 32, 64);
                p[q] = pp;       // sum over n in this wave, for bl = bh*4+q
            }
            if (eq == 0) {
                #pragma unroll
                for (int q = 0; q < 4; ++q)
                    wsum[ii & 1][w][bh * 4 + q] = p[q];
            }
            __syncthreads();     // the ONLY barrier per i (wsum double-buffered)
            #pragma unroll
            for (int q = 0; q < 4; ++q) {
                const int bl = bh * 4 + q;
                float s = wsum[ii & 1][0][bl] + wsum[ii & 1][1][bl]
                        + wsum[ii & 1][2][bl] + wsum[ii & 1][3][bl];
                float c = e[q] / s;
                fma4(sacc[q], c, u[q]);
            }
        }
    }

    // ---- write partials: P[ic][b][o] (64B-coalesced) ----
    #pragma unroll
    for (int q = 0; q < 4; ++q)
        *(float4*)&P[((size_t)ic * B_TOT + b0 + bh * 4 + q) * OD + n * EV + eq * 4] = sacc[q];
}

// Reduce partials over 256 i-chunks, then squash per (b, n).
// Grid: 64 b x 8 output-slices = 512 blocks (2/CU, all CUs busy).
// Block: 256 threads = 64 outputs x 4 ic-quarters; LDS combine; 64 survivors
// do the squash (norm over the 16-lane e-group) and store.
// If addsrc != null, out = squash(...) + addsrc  (used to produce v0+v1).
__global__ __launch_bounds__(256, 8)
void reduce_squash(const float* __restrict__ P, float* __restrict__ dst,
                   const float* __restrict__ addsrc, float pre)
{
    __shared__ float red[256];
    const int b   = blockIdx.x >> 3;
    const int oq  = blockIdx.x & 7;
    const int t   = threadIdx.x;
    const int o   = oq * 64 + (t & 63);
    const int icq = t >> 6;                       // 0..3
    const size_t stride = (size_t)B_TOT * OD;     // per-ic stride in floats

    float s = 0.f;
    size_t base = ((size_t)(icq * 64) * B_TOT + b) * OD + o;
    #pragma unroll 8
    for (int k = 0; k < 64; ++k) s += P[base + (size_t)k * stride];
    red[t] = s;
    __syncthreads();

    if (t < 64) {
        float v = red[t] + red[t + 64] + red[t + 128] + red[t + 192];
        v *= pre;
        // squared norm over e (16 consecutive lanes = one capsule)
        float q2 = v * v;
        q2 += __shfl_xor(q2, 1, 64);
        q2 += __shfl_xor(q2, 2, 64);
        q2 += __shfl_xor(q2, 4, 64);
        q2 += __shfl_xor(q2, 8, 64);
        float sc = q2 / ((1.0f + q2) * sqrtf(q2));
        float outv = v * sc;
        if (addsrc) outv += addsrc[b * OD + o];
        dst[b * OD + o] = outv;
    }
}

extern "C" void kernel_launch(void* const* d_in, const int* in_sizes, int n_in,
                              void* d_out, int out_size, void* d_ws, size_t ws_size,
                              hipStream_t stream) {
    const float* x = (const float*)d_in[0];
    const float* W = (const float*)d_in[1];
    float* out = (float*)d_out;

    char* ws = (char*)d_ws;
    float* P  = (float*)ws;                               // NIC*64*512*4 = 32 MB
    float* v0 = (float*)(ws + (size_t)32 * 1024 * 1024);  // 64*512*4 = 128 KB
    float* vs = v0 + B_TOT * OD;                          // v0 + v1

    dim3 rg(NBC * NIC), rb(256);   // 2048 blocks = 8 per CU = 32 waves/CU
    dim3 sg(B_TOT * 8), sb(256);   // 512 blocks

    // iter 0: uniform c = 1/32
    route_pass<0><<<rg, rb, 0, stream>>>(x, W, P, nullptr);
    reduce_squash<<<sg, sb, 0, stream>>>(P, v0, nullptr, 1.0f / 32.0f);
    // iter 1: c = softmax(u.v0)
    route_pass<1><<<rg, rb, 0, stream>>>(x, W, P, v0);
    // vs = v0 + v1  (iter-2 logits: u.v0 + u.v1 = u.(v0+v1))
    reduce_squash<<<sg, sb, 0, stream>>>(P, vs, v0, 1.0f);
    // iter 2: c = softmax(u.(v0+v1)); final
    route_pass<1><<<rg, rb, 0, stream>>>(x, W, P, vs);
    reduce_squash<<<sg, sb, 0, stream>>>(P, out, nullptr, 1.0f);
}

// Round 2
// 517.270 us; speedup vs baseline: 1.3178x; 1.3178x over previous
//
#include <hip/hip_runtime.h>
#include <math.h>

// CapsLayer dynamic routing, MI355X fp32.
// x: [64, 2048, 8]  W: [2048, 32, 8, 16]  out: [64, 32, 16]
// Never materialize u_hat (256 MB); recompute per routing pass.
// R4: fix R3's catastrophic register spill. R3 demanded __launch_bounds__(256,8)
// -> 64-VGPR cap -> compiler spilled ~60 regs to scratch -> 1.4 GB/pass of
// scratch HBM traffic (FETCH 800MB, WRITE 568MB, VALUBusy 2%). Revert to
// (256,4): natural allocation is ~36 VGPR (R2-measured), which still permits
// 8 blocks/CU co-residency from the 2048-block grid — launch_bounds' 2nd arg
// is an allocator floor, not an occupancy ceiling.
// Kept from R3 (sound, not the regression):
//   * ICH=8: grid 2048 = 8 blocks/CU schedulable (TLP to hide L2 latency).
//   * aws eliminated: iter2 logits u.v0 + u.v1 == u.(v0+v1) (dot linearity).
//   * reduce_squash parallel: 512 blocks, 4-way ic split + LDS combine.

#define B_TOT 64
#define I_TOT 2048
#define D_IN  8
#define NC    32
#define EV    16
#define OD    (NC*EV)      // 512 outputs per b
#define BC    8            // batch rows per block
#define NBC   (B_TOT/BC)   // 8 b-chunks
#define ICH   8            // i's per block
#define NIC   (I_TOT/ICH)  // 256 i-chunks

__device__ __forceinline__ void fma4(float4& acc, float a, const float4& w) {
    acc.x = fmaf(a, w.x, acc.x);
    acc.y = fmaf(a, w.y, acc.y);
    acc.z = fmaf(a, w.z, acc.z);
    acc.w = fmaf(a, w.w, acc.w);
}

// MODE 0: c uniform (iter 0)              -> P partials
// MODE 1: c = softmax_n(u . vin)          -> P partials
//         (iter 2 uses vin = v0+v1: dot is linear, so no logit carry needed)
template <int MODE>
__global__ __launch_bounds__(256, 4)   // 4 = allocator floor; ~36 VGPR natural
void route_pass(const float* __restrict__ x, const float* __restrict__ W,
                float* __restrict__ P, const float* __restrict__ vin)
{
    __shared__ __align__(16) float xl[BC * ICH * D_IN];   // 2 KB
    __shared__ float wsum[2][4][BC];                      // 256 B (double-buffered)

    const int t  = threadIdx.x;
    // XCD swizzle: blk%8 == ic%8 (256 ≡ 0 mod 8), so the 8 bc-siblings of an
    // ic (which share W[i0..i0+7]) land on the same XCD's L2.
    const int ic = blockIdx.x & (NIC - 1);   // 0..255
    const int bc = blockIdx.x >> 8;          // 0..7
    const int b0 = bc * BC;
    const int i0 = ic * ICH;
    const int eq = t & 3;          // e quarter (4 e's)
    const int bh = (t >> 2) & 1;   // b half (4 b's each)
    const int n  = t >> 3;         // capsule 0..31
    const int w  = t >> 6;         // wave 0..3

    // ---- stage x[b0..b0+7][i0..i0+7][0..7] once (2 KB) ----
    if (t < 128) {
        const int row = t >> 4, f = (t & 15) * 4;
        *(float4*)&xl[row * (ICH * D_IN) + f] =
            *(const float4*)&x[((size_t)(b0 + row) * I_TOT + i0) * D_IN + f];
    }

    // ---- v fragments in registers (loaded once; L2-hot, tiny) ----
    float4 vr[4];
    if (MODE == 1) {
        #pragma unroll
        for (int q = 0; q < 4; ++q)
            vr[q] = *(const float4*)&vin[(size_t)(b0 + bh * 4 + q) * OD + n * EV + eq * 4];
    }
    __syncthreads();

    float4 sacc[4];
    #pragma unroll
    for (int q = 0; q < 4; ++q) sacc[q] = make_float4(0.f, 0.f, 0.f, 0.f);

    const float* Wt = &W[(size_t)i0 * 4096 + n * 128 + eq * 4];

    for (int ii = 0; ii < ICH; ++ii) {
        // ---- this thread's W fragment straight from global (64B-coalesced) ----
        float4 wr[8];
        #pragma unroll
        for (int d = 0; d < 8; ++d)
            wr[d] = *(const float4*)&Wt[ii * 4096 + d * 16];

        // ---- u[bl][eq*4..+3] for 4 batch rows ----
        float4 u[4];
        #pragma unroll
        for (int q = 0; q < 4; ++q) {
            const int bl = bh * 4 + q;
            float4 xa = *(float4*)&xl[bl * (ICH * D_IN) + ii * 8];
            float4 xb = *(float4*)&xl[bl * (ICH * D_IN) + ii * 8 + 4];
            float4 uu = make_float4(0.f, 0.f, 0.f, 0.f);
            fma4(uu, xa.x, wr[0]); fma4(uu, xa.y, wr[1]);
            fma4(uu, xa.z, wr[2]); fma4(uu, xa.w, wr[3]);
            fma4(uu, xb.x, wr[4]); fma4(uu, xb.y, wr[5]);
            fma4(uu, xb.z, wr[6]); fma4(uu, xb.w, wr[7]);
            u[q] = uu;
        }

        if (MODE == 0) {
            #pragma unroll
            for (int q = 0; q < 4; ++q) {
                sacc[q].x += u[q].x; sacc[q].y += u[q].y;
                sacc[q].z += u[q].z; sacc[q].w += u[q].w;
            }
            // no barrier: xl is read-only, no LDS communication
        } else {
            // ---- a[bl] = dot(u, v) over e: 4 in-thread + shfl over eq bits ----
            float a[4];
            #pragma unroll
            for (int q = 0; q < 4; ++q) {
                float ap = u[q].x * vr[q].x + u[q].y * vr[q].y
                         + u[q].z * vr[q].z + u[q].w * vr[q].w;
                ap += __shfl_xor(ap, 1, 64);
                ap += __shfl_xor(ap, 2, 64);
                a[q] = ap;
            }
            // ---- softmax over n: exp, in-wave partial over this wave's 8 n's ----
            float e[4], p[4];
            #pragma unroll
            for (int q = 0; q < 4; ++q) {
                e[q] = __expf(a[q]);
                float pp = e[q];
                pp += __shfl_xor(pp, 8, 64);
                pp += __shfl_xor(pp, 16, 64);
                pp += __shfl_xor(pp, 32, 64);
                p[q] = pp;       // sum over n in this wave, for bl = bh*4+q
            }
            if (eq == 0) {
                #pragma unroll
                for (int q = 0; q < 4; ++q)
                    wsum[ii & 1][w][bh * 4 + q] = p[q];
            }
            __syncthreads();     // the ONLY barrier per i (wsum double-buffered)
            #pragma unroll
            for (int q = 0; q < 4; ++q) {
                const int bl = bh * 4 + q;
                float s = wsum[ii & 1][0][bl] + wsum[ii & 1][1][bl]
                        + wsum[ii & 1][2][bl] + wsum[ii & 1][3][bl];
                float c = e[q] / s;
                fma4(sacc[q], c, u[q]);
            }
        }
    }

    // ---- write partials: P[ic][b][o] (64B-coalesced, full 128B lines/wave) ----
    #pragma unroll
    for (int q = 0; q < 4; ++q)
        *(float4*)&P[((size_t)ic * B_TOT + b0 + bh * 4 + q) * OD + n * EV + eq * 4] = sacc[q];
}

// Reduce partials over 256 i-chunks, then squash per (b, n).
// Grid: 64 b x 8 output-slices = 512 blocks (2/CU, all CUs busy).
// Block: 256 threads = 64 outputs x 4 ic-quarters; LDS combine; 64 survivors
// do the squash (norm over the 16-lane e-group) and store.
// If addsrc != null, out = squash(...) + addsrc  (used to produce v0+v1).
__global__ __launch_bounds__(256, 4)
void reduce_squash(const float* __restrict__ P, float* __restrict__ dst,
                   const float* __restrict__ addsrc, float pre)
{
    __shared__ float red[256];
    const int b   = blockIdx.x >> 3;
    const int oq  = blockIdx.x & 7;
    const int t   = threadIdx.x;
    const int o   = oq * 64 + (t & 63);
    const int icq = t >> 6;                       // 0..3
    const size_t stride = (size_t)B_TOT * OD;     // per-ic stride in floats

    float s = 0.f;
    size_t base = ((size_t)(icq * 64) * B_TOT + b) * OD + o;
    #pragma unroll 8
    for (int k = 0; k < 64; ++k) s += P[base + (size_t)k * stride];
    red[t] = s;
    __syncthreads();

    if (t < 64) {
        float v = red[t] + red[t + 64] + red[t + 128] + red[t + 192];
        v *= pre;
        // squared norm over e (16 consecutive lanes = one capsule)
        float q2 = v * v;
        q2 += __shfl_xor(q2, 1, 64);
        q2 += __shfl_xor(q2, 2, 64);
        q2 += __shfl_xor(q2, 4, 64);
        q2 += __shfl_xor(q2, 8, 64);
        float sc = q2 / ((1.0f + q2) * sqrtf(q2));
        float outv = v * sc;
        if (addsrc) outv += addsrc[b * OD + o];
        dst[b * OD + o] = outv;
    }
}

extern "C" void kernel_launch(void* const* d_in, const int* in_sizes, int n_in,
                              void* d_out, int out_size, void* d_ws, size_t ws_size,
                              hipStream_t stream) {
    const float* x = (const float*)d_in[0];
    const float* W = (const float*)d_in[1];
    float* out = (float*)d_out;

    char* ws = (char*)d_ws;
    float* P  = (float*)ws;                               // NIC*64*512*4 = 32 MB
    float* v0 = (float*)(ws + (size_t)32 * 1024 * 1024);  // 64*512*4 = 128 KB
    float* vs = v0 + B_TOT * OD;                          // v0 + v1

    dim3 rg(NBC * NIC), rb(256);   // 2048 blocks; 8/CU schedulable at ~36 VGPR
    dim3 sg(B_TOT * 8), sb(256);   // 512 blocks

    // iter 0: uniform c = 1/32
    route_pass<0><<<rg, rb, 0, stream>>>(x, W, P, nullptr);
    reduce_squash<<<sg, sb, 0, stream>>>(P, v0, nullptr, 1.0f / 32.0f);
    // iter 1: c = softmax(u.v0)
    route_pass<1><<<rg, rb, 0, stream>>>(x, W, P, v0);
    // vs = v0 + v1  (iter-2 logits: u.v0 + u.v1 = u.(v0+v1))
    reduce_squash<<<sg, sb, 0, stream>>>(P, vs, v0, 1.0f);
    // iter 2: c = softmax(u.(v0+v1)); final
    route_pass<1><<<rg, rb, 0, stream>>>(x, W, P, vs);
    reduce_squash<<<sg, sb, 0, stream>>>(P, out, nullptr, 1.0f);
}

// Round 3
// 196.406 us; speedup vs baseline: 3.4706x; 2.6337x over previous
//
#include <hip/hip_runtime.h>
#include <math.h>

// CapsLayer dynamic routing, MI355X fp32.
// x: [64, 2048, 8]  W: [2048, 32, 8, 16]  out: [64, 32, 16]
// Never materialize u_hat (256 MB); recompute per routing pass.
// R5: kill the REAL spill source. R3/R4's 1.1 GB/pass HBM traffic was NOT
// launch_bounds: ICH 16->8 made the ii-loop fully unrollable, so the compiler
// hoisted 8x8 float4 W loads (=256 VGPRs) and spilled them to scratch
// (~1 KB/thread x 524K resident threads = ~500 MB > L3 -> HBM round-trips;
// matches FETCH 600 MB / WRITE 500 MB / VALUBusy 2.8%).
// Fix: #pragma unroll 1 on the ii loop. Per-iteration live set ~36-48 VGPR.
// Kept: 2048-block grid (8 blocks/CU TLP), aws elimination via dot linearity,
// parallel 512-block reduce_squash.

#define B_TOT 64
#define I_TOT 2048
#define D_IN  8
#define NC    32
#define EV    16
#define OD    (NC*EV)      // 512 outputs per b
#define BC    8            // batch rows per block
#define NBC   (B_TOT/BC)   // 8 b-chunks
#define ICH   8            // i's per block
#define NIC   (I_TOT/ICH)  // 256 i-chunks

__device__ __forceinline__ void fma4(float4& acc, float a, const float4& w) {
    acc.x = fmaf(a, w.x, acc.x);
    acc.y = fmaf(a, w.y, acc.y);
    acc.z = fmaf(a, w.z, acc.z);
    acc.w = fmaf(a, w.w, acc.w);
}

// MODE 0: c uniform (iter 0)              -> P partials
// MODE 1: c = softmax_n(u . vin)          -> P partials
//         (iter 2 uses vin = v0+v1: dot is linear, so no logit carry needed)
template <int MODE>
__global__ __launch_bounds__(256, 4)
void route_pass(const float* __restrict__ x, const float* __restrict__ W,
                float* __restrict__ P, const float* __restrict__ vin)
{
    __shared__ __align__(16) float xl[BC * ICH * D_IN];   // 2 KB
    __shared__ float wsum[2][4][BC];                      // 256 B (double-buffered)

    const int t  = threadIdx.x;
    // XCD swizzle: blk%8 == ic%8 (NIC = 256 ≡ 0 mod 8), so the 8 bc-siblings
    // of an ic (which share W[i0..i0+7]) land on the same XCD's L2.
    const int ic = blockIdx.x & (NIC - 1);   // 0..255
    const int bc = blockIdx.x >> 8;          // 0..7
    const int b0 = bc * BC;
    const int i0 = ic * ICH;
    const int eq = t & 3;          // e quarter (4 e's)
    const int bh = (t >> 2) & 1;   // b half (4 b's each)
    const int n  = t >> 3;         // capsule 0..31
    const int w  = t >> 6;         // wave 0..3

    // ---- stage x[b0..b0+7][i0..i0+7][0..7] once (2 KB) ----
    if (t < 128) {
        const int row = t >> 4, f = (t & 15) * 4;
        *(float4*)&xl[row * (ICH * D_IN) + f] =
            *(const float4*)&x[((size_t)(b0 + row) * I_TOT + i0) * D_IN + f];
    }

    // ---- v fragments in registers (loaded once; L2-hot, tiny) ----
    float4 vr[4];
    if (MODE == 1) {
        #pragma unroll
        for (int q = 0; q < 4; ++q)
            vr[q] = *(const float4*)&vin[(size_t)(b0 + bh * 4 + q) * OD + n * EV + eq * 4];
    }
    __syncthreads();

    float4 sacc[4];
    #pragma unroll
    for (int q = 0; q < 4; ++q) sacc[q] = make_float4(0.f, 0.f, 0.f, 0.f);

    const float* Wt = &W[(size_t)i0 * 4096 + n * 128 + eq * 4];

    // unroll 1 is load-bearing: with ICH=8 the unroller otherwise flattens
    // this loop and hoists 64 float4 W loads -> 256 VGPRs -> scratch spill
    // (R3/R4: 1.1 GB/pass HBM, VALUBusy 2.8%). Keep per-iter live set small;
    // latency is hidden by TLP (8 blocks/CU), not ILP.
    #pragma unroll 1
    for (int ii = 0; ii < ICH; ++ii) {
        // ---- this thread's W fragment straight from global (64B-coalesced) ----
        float4 wr[8];
        #pragma unroll
        for (int d = 0; d < 8; ++d)
            wr[d] = *(const float4*)&Wt[ii * 4096 + d * 16];

        // ---- u[bl][eq*4..+3] for 4 batch rows ----
        float4 u[4];
        #pragma unroll
        for (int q = 0; q < 4; ++q) {
            const int bl = bh * 4 + q;
            float4 xa = *(float4*)&xl[bl * (ICH * D_IN) + ii * 8];
            float4 xb = *(float4*)&xl[bl * (ICH * D_IN) + ii * 8 + 4];
            float4 uu = make_float4(0.f, 0.f, 0.f, 0.f);
            fma4(uu, xa.x, wr[0]); fma4(uu, xa.y, wr[1]);
            fma4(uu, xa.z, wr[2]); fma4(uu, xa.w, wr[3]);
            fma4(uu, xb.x, wr[4]); fma4(uu, xb.y, wr[5]);
            fma4(uu, xb.z, wr[6]); fma4(uu, xb.w, wr[7]);
            u[q] = uu;
        }

        if (MODE == 0) {
            #pragma unroll
            for (int q = 0; q < 4; ++q) {
                sacc[q].x += u[q].x; sacc[q].y += u[q].y;
                sacc[q].z += u[q].z; sacc[q].w += u[q].w;
            }
            // no barrier: xl is read-only, no LDS communication
        } else {
            // ---- a[bl] = dot(u, v) over e: 4 in-thread + shfl over eq bits ----
            float a[4];
            #pragma unroll
            for (int q = 0; q < 4; ++q) {
                float ap = u[q].x * vr[q].x + u[q].y * vr[q].y
                         + u[q].z * vr[q].z + u[q].w * vr[q].w;
                ap += __shfl_xor(ap, 1, 64);
                ap += __shfl_xor(ap, 2, 64);
                a[q] = ap;
            }
            // ---- softmax over n: exp, in-wave partial over this wave's 8 n's ----
            float e[4], p[4];
            #pragma unroll
            for (int q = 0; q < 4; ++q) {
                e[q] = __expf(a[q]);
                float pp = e[q];
                pp += __shfl_xor(pp, 8, 64);
                pp += __shfl_xor(pp, 16, 64);
                pp += __shfl_xor(pp, 32, 64);
                p[q] = pp;       // sum over n in this wave, for bl = bh*4+q
            }
            if (eq == 0) {
                #pragma unroll
                for (int q = 0; q < 4; ++q)
                    wsum[ii & 1][w][bh * 4 + q] = p[q];
            }
            __syncthreads();     // the ONLY barrier per i (wsum double-buffered)
            #pragma unroll
            for (int q = 0; q < 4; ++q) {
                const int bl = bh * 4 + q;
                float s = wsum[ii & 1][0][bl] + wsum[ii & 1][1][bl]
                        + wsum[ii & 1][2][bl] + wsum[ii & 1][3][bl];
                float c = e[q] / s;
                fma4(sacc[q], c, u[q]);
            }
        }
    }

    // ---- write partials: P[ic][b][o] (64B-coalesced, full 128B lines/wave) ----
    #pragma unroll
    for (int q = 0; q < 4; ++q)
        *(float4*)&P[((size_t)ic * B_TOT + b0 + bh * 4 + q) * OD + n * EV + eq * 4] = sacc[q];
}

// Reduce partials over 256 i-chunks, then squash per (b, n).
// Grid: 64 b x 8 output-slices = 512 blocks (2/CU, all CUs busy).
// Block: 256 threads = 64 outputs x 4 ic-quarters; LDS combine; 64 survivors
// do the squash (norm over the 16-lane e-group) and store.
// If addsrc != null, out = squash(...) + addsrc  (used to produce v0+v1).
__global__ __launch_bounds__(256, 4)
void reduce_squash(const float* __restrict__ P, float* __restrict__ dst,
                   const float* __restrict__ addsrc, float pre)
{
    __shared__ float red[256];
    const int b   = blockIdx.x >> 3;
    const int oq  = blockIdx.x & 7;
    const int t   = threadIdx.x;
    const int o   = oq * 64 + (t & 63);
    const int icq = t >> 6;                       // 0..3
    const size_t stride = (size_t)B_TOT * OD;     // per-ic stride in floats

    float s = 0.f;
    size_t base = ((size_t)(icq * 64) * B_TOT + b) * OD + o;
    #pragma unroll 8
    for (int k = 0; k < 64; ++k) s += P[base + (size_t)k * stride];
    red[t] = s;
    __syncthreads();

    if (t < 64) {
        float v = red[t] + red[t + 64] + red[t + 128] + red[t + 192];
        v *= pre;
        // squared norm over e (16 consecutive lanes = one capsule)
        float q2 = v * v;
        q2 += __shfl_xor(q2, 1, 64);
        q2 += __shfl_xor(q2, 2, 64);
        q2 += __shfl_xor(q2, 4, 64);
        q2 += __shfl_xor(q2, 8, 64);
        float sc = q2 / ((1.0f + q2) * sqrtf(q2));
        float outv = v * sc;
        if (addsrc) outv += addsrc[b * OD + o];
        dst[b * OD + o] = outv;
    }
}

extern "C" void kernel_launch(void* const* d_in, const int* in_sizes, int n_in,
                              void* d_out, int out_size, void* d_ws, size_t ws_size,
                              hipStream_t stream) {
    const float* x = (const float*)d_in[0];
    const float* W = (const float*)d_in[1];
    float* out = (float*)d_out;

    char* ws = (char*)d_ws;
    float* P  = (float*)ws;                               // NIC*64*512*4 = 32 MB
    float* v0 = (float*)(ws + (size_t)32 * 1024 * 1024);  // 64*512*4 = 128 KB
    float* vs = v0 + B_TOT * OD;                          // v0 + v1

    dim3 rg(NBC * NIC), rb(256);   // 2048 blocks; 8/CU schedulable at ~40 VGPR
    dim3 sg(B_TOT * 8), sb(256);   // 512 blocks

    // iter 0: uniform c = 1/32
    route_pass<0><<<rg, rb, 0, stream>>>(x, W, P, nullptr);
    reduce_squash<<<sg, sb, 0, stream>>>(P, v0, nullptr, 1.0f / 32.0f);
    // iter 1: c = softmax(u.v0)
    route_pass<1><<<rg, rb, 0, stream>>>(x, W, P, v0);
    // vs = v0 + v1  (iter-2 logits: u.v0 + u.v1 = u.(v0+v1))
    reduce_squash<<<sg, sb, 0, stream>>>(P, vs, v0, 1.0f);
    // iter 2: c = softmax(u.(v0+v1)); final
    route_pass<1><<<rg, rb, 0, stream>>>(x, W, P, vs);
    reduce_squash<<<sg, sb, 0, stream>>>(P, out, nullptr, 1.0f);
}